// Round 1
// baseline (482.394 us; speedup 1.0000x reference)
//
#include <hip/hip_runtime.h>

// Problem constants
#define Bb 4
#define Tt 2048
#define Cc 1024
#define Hh 16
#define HDim 64
#define NQKV 3072
#define Mtot 8192   // B*T

typedef __bf16 bf16_t;
typedef __bf16 bf16x8 __attribute__((ext_vector_type(8)));
typedef float f32x4 __attribute__((ext_vector_type(4)));

// ---------------------------------------------------------------------------
// GEMM (NT): out[m][n] = sum_k A[m][k] * Bm[n][k] + bias[n]
// A: [M][K] f32 row-major, Bm: [N][K] f32 row-major. M,N mult of 64, K mult 32.
// Block: 256 thr (4 waves, 2x2 wave grid, 32x32 per wave via 2x2 16x16 frags).
// ---------------------------------------------------------------------------
__global__ __launch_bounds__(256) void gemm_nt_bias(
    const float* __restrict__ A, const float* __restrict__ Bm,
    const float* __restrict__ bias, float* __restrict__ Cout,
    int M, int N, int K)
{
  __shared__ __attribute__((aligned(16))) bf16_t lds_a[64][40];  // +8 pad
  __shared__ __attribute__((aligned(16))) bf16_t lds_b[64][40];

  const int tid  = threadIdx.x;
  const int lane = tid & 63;
  const int wid  = tid >> 6;          // 0..3
  const int wr   = (wid >> 1) * 32;   // wave row offset in tile
  const int wc   = (wid & 1) * 32;    // wave col offset in tile
  const int l15  = lane & 15;
  const int lh   = lane >> 4;         // 0..3
  const int bm   = blockIdx.x * 64;
  const int bn   = blockIdx.y * 64;

  f32x4 acc[2][2] = {};

  const int srow = tid >> 2;          // 0..63
  const int sseg = (tid & 3) * 8;     // 0,8,16,24

  const float* pa = A  + (size_t)(bm + srow) * K + sseg;
  const float* pb = Bm + (size_t)(bn + srow) * K + sseg;

  for (int k0 = 0; k0 < K; k0 += 32) {
    // stage A,B tiles (f32 -> bf16)
    float av_[8], bv_[8];
    *(float4*)&av_[0] = *(const float4*)(pa);
    *(float4*)&av_[4] = *(const float4*)(pa + 4);
    *(float4*)&bv_[0] = *(const float4*)(pb);
    *(float4*)&bv_[4] = *(const float4*)(pb + 4);
    pa += 32; pb += 32;
    bf16x8 av, bv;
#pragma unroll
    for (int i = 0; i < 8; i++) { av[i] = (bf16_t)av_[i]; bv[i] = (bf16_t)bv_[i]; }
    *(bf16x8*)&lds_a[srow][sseg] = av;
    *(bf16x8*)&lds_b[srow][sseg] = bv;
    __syncthreads();

    bf16x8 af[2], bfv[2];
#pragma unroll
    for (int mi = 0; mi < 2; mi++)
      af[mi] = *(const bf16x8*)&lds_a[wr + mi*16 + l15][lh * 8];
#pragma unroll
    for (int ni = 0; ni < 2; ni++)
      bfv[ni] = *(const bf16x8*)&lds_b[wc + ni*16 + l15][lh * 8];
#pragma unroll
    for (int mi = 0; mi < 2; mi++)
#pragma unroll
      for (int ni = 0; ni < 2; ni++)
        acc[mi][ni] = __builtin_amdgcn_mfma_f32_16x16x32_bf16(
            af[mi], bfv[ni], acc[mi][ni], 0, 0, 0);
    __syncthreads();
  }

  // epilogue: C/D layout col = lane&15, row = (lane>>4)*4 + reg
#pragma unroll
  for (int mi = 0; mi < 2; mi++) {
#pragma unroll
    for (int ni = 0; ni < 2; ni++) {
      const int col = bn + wc + ni*16 + l15;
      const float bs = bias[col];
#pragma unroll
      for (int r = 0; r < 4; r++) {
        const int row = bm + wr + mi*16 + lh*4 + r;
        Cout[(size_t)row * N + col] = acc[mi][ni][r] + bs;
      }
    }
  }
}

// ---------------------------------------------------------------------------
// Causal flash attention. qkv: [B,T,3C] f32 (q|k|v each C=1024, head h at h*64).
// y: [B,T,C] f32. Block: 256 thr = 4 waves; each wave owns 16 q rows;
// block processes 64 q rows, iterating 64-key tiles with online softmax.
// ---------------------------------------------------------------------------
__global__ __launch_bounds__(256) void attn_kernel(
    const float* __restrict__ qkv, float* __restrict__ y)
{
  __shared__ __attribute__((aligned(16))) bf16_t lds_k [64][72]; // [key][d]
  __shared__ __attribute__((aligned(16))) bf16_t lds_vt[64][72]; // [d][key]
  __shared__ __attribute__((aligned(16))) bf16_t lds_p [4][16][72]; // per-wave [q][key]

  const int tid  = threadIdx.x;
  const int lane = tid & 63;
  const int w    = tid >> 6;      // wave 0..3
  const int l15  = lane & 15;
  const int lh   = lane >> 4;     // 0..3
  const int qb   = blockIdx.x;    // 0..31 (q tile)
  const int qbase = qb * 64;
  const int bh   = blockIdx.y;    // 0..63
  const int b    = bh >> 4;
  const int h    = bh & 15;

  const float* qp = qkv + (size_t)b * Tt * NQKV + h * HDim;
  const float* kp = qp + Cc;
  const float* vp = qp + 2 * Cc;

  // Q fragments (A layout: row = lane&15 within wave's 16 rows, k = lh*8+j),
  // scaled by 1/sqrt(64) folded in before bf16 rounding.
  bf16x8 qf[2];
  {
    const float* qrow = qp + (size_t)(qbase + w*16 + l15) * NQKV;
#pragma unroll
    for (int ka = 0; ka < 2; ka++) {
      float qq[8];
      *(float4*)&qq[0] = *(const float4*)(qrow + ka*32 + lh*8);
      *(float4*)&qq[4] = *(const float4*)(qrow + ka*32 + lh*8 + 4);
#pragma unroll
      for (int i = 0; i < 8; i++) qf[ka][i] = (bf16_t)(qq[i] * 0.125f);
    }
  }

  f32x4 o_acc[4] = {};
  float m_run[4], l_run[4];
#pragma unroll
  for (int r = 0; r < 4; r++) { m_run[r] = -1e30f; l_run[r] = 0.0f; }

  const int ktiles = qb + 1;
  for (int kt = 0; kt < ktiles; kt++) {
    __syncthreads();  // prev iter's PV reads of lds_vt/lds_p done
    // ---- stage K tile [key][d] and V^T tile [d][key] ----
    {
      const int key  = tid >> 2;
      const int dseg = (tid & 3) * 16;
      const float* krow = kp + (size_t)(kt*64 + key) * NQKV + dseg;
      const float* vrow = vp + (size_t)(kt*64 + key) * NQKV + dseg;
      float kk[16], vv[16];
#pragma unroll
      for (int i = 0; i < 4; i++) {
        *(float4*)&kk[i*4] = ((const float4*)krow)[i];
        *(float4*)&vv[i*4] = ((const float4*)vrow)[i];
      }
      bf16x8 kv0, kv1;
#pragma unroll
      for (int i = 0; i < 8; i++) { kv0[i] = (bf16_t)kk[i]; kv1[i] = (bf16_t)kk[8+i]; }
      *(bf16x8*)&lds_k[key][dseg]     = kv0;
      *(bf16x8*)&lds_k[key][dseg + 8] = kv1;
#pragma unroll
      for (int i = 0; i < 16; i++) lds_vt[dseg + i][key] = (bf16_t)vv[i];
    }
    __syncthreads();

    // ---- S = Q K^T (scaled) ----
    f32x4 s[4] = {};
#pragma unroll
    for (int fc = 0; fc < 4; fc++) {
#pragma unroll
      for (int ka = 0; ka < 2; ka++) {
        bf16x8 kf = *(const bf16x8*)&lds_k[fc*16 + l15][ka*32 + lh*8];
        s[fc] = __builtin_amdgcn_mfma_f32_16x16x32_bf16(qf[ka], kf, s[fc], 0, 0, 0);
      }
    }

    // ---- causal mask (only diagonal tile needs it) ----
    if (kt == ktiles - 1) {
#pragma unroll
      for (int fc = 0; fc < 4; fc++) {
        const int key = kt*64 + fc*16 + l15;
#pragma unroll
        for (int r = 0; r < 4; r++) {
          const int q = qbase + w*16 + lh*4 + r;
          if (key > q) s[fc][r] = -1e30f;
        }
      }
    }

    // ---- online softmax update (rows live in 16-lane groups) ----
    float rm[4];
#pragma unroll
    for (int r = 0; r < 4; r++)
      rm[r] = fmaxf(fmaxf(s[0][r], s[1][r]), fmaxf(s[2][r], s[3][r]));
#pragma unroll
    for (int msk = 1; msk < 16; msk <<= 1)
#pragma unroll
      for (int r = 0; r < 4; r++)
        rm[r] = fmaxf(rm[r], __shfl_xor(rm[r], msk));

    float al[4], rs[4];
#pragma unroll
    for (int r = 0; r < 4; r++) {
      const float mn = fmaxf(m_run[r], rm[r]);
      al[r] = __expf(m_run[r] - mn);
      m_run[r] = mn;
      rs[r] = 0.0f;
    }
#pragma unroll
    for (int fc = 0; fc < 4; fc++) {
#pragma unroll
      for (int r = 0; r < 4; r++) {
        const float p = __expf(s[fc][r] - m_run[r]);
        rs[r] += p;
        lds_p[w][lh*4 + r][fc*16 + l15] = (bf16_t)p;
      }
    }
#pragma unroll
    for (int msk = 1; msk < 16; msk <<= 1)
#pragma unroll
      for (int r = 0; r < 4; r++)
        rs[r] += __shfl_xor(rs[r], msk);
#pragma unroll
    for (int r = 0; r < 4; r++) l_run[r] = l_run[r] * al[r] + rs[r];
#pragma unroll
    for (int fd = 0; fd < 4; fd++)
#pragma unroll
      for (int r = 0; r < 4; r++) o_acc[fd][r] *= al[r];

    __syncthreads();  // P visible (also orders within-wave write->read)

    // ---- O += P V ----
#pragma unroll
    for (int ka = 0; ka < 2; ka++) {
      bf16x8 pf = *(const bf16x8*)&lds_p[w][l15][ka*32 + lh*8];
#pragma unroll
      for (int fd = 0; fd < 4; fd++) {
        bf16x8 vf = *(const bf16x8*)&lds_vt[fd*16 + l15][ka*32 + lh*8];
        o_acc[fd] = __builtin_amdgcn_mfma_f32_16x16x32_bf16(pf, vf, o_acc[fd], 0, 0, 0);
      }
    }
  }

  // ---- epilogue: y[b,t,h*64+d] = O/l ----
#pragma unroll
  for (int fd = 0; fd < 4; fd++) {
#pragma unroll
    for (int r = 0; r < 4; r++) {
      const int t = qbase + w*16 + lh*4 + r;
      const int d = fd*16 + l15;
      y[((size_t)b * Tt + t) * Cc + h * HDim + d] = o_acc[fd][r] / l_run[r];
    }
  }
}

// ---------------------------------------------------------------------------
extern "C" void kernel_launch(void* const* d_in, const int* in_sizes, int n_in,
                              void* d_out, int out_size, void* d_ws, size_t ws_size,
                              hipStream_t stream) {
  const float* x      = (const float*)d_in[0];
  const float* w_attn = (const float*)d_in[1];
  const float* b_attn = (const float*)d_in[2];
  const float* w_proj = (const float*)d_in[3];
  const float* b_proj = (const float*)d_in[4];
  float* out = (float*)d_out;

  const size_t qkv_bytes = (size_t)Mtot * NQKV * sizeof(float);  // 96 MB
  const size_t y_bytes   = (size_t)Mtot * Cc * sizeof(float);    // 32 MB
  float* qkv = (float*)d_ws;
  const bool big = ws_size >= qkv_bytes + y_bytes;
  float* y = big ? (float*)((char*)d_ws + qkv_bytes) : out;

  // 1) QKV projection
  gemm_nt_bias<<<dim3(Mtot/64, NQKV/64), 256, 0, stream>>>(
      x, w_attn, b_attn, qkv, Mtot, NQKV, Cc);

  // 2) causal attention
  attn_kernel<<<dim3(Tt/64, Bb*Hh), 256, 0, stream>>>(qkv, y);

  // 3) output projection
  if (big) {
    gemm_nt_bias<<<dim3(Mtot/64, Cc/64), 256, 0, stream>>>(
        y, w_proj, b_proj, out, Mtot, Cc, Cc);
  } else {
    float* tmp = (float*)d_ws;  // reuse qkv region (attention is done with it)
    gemm_nt_bias<<<dim3(Mtot/64, Cc/64), 256, 0, stream>>>(
        y, w_proj, b_proj, tmp, Mtot, Cc, Cc);
    hipMemcpyAsync(out, tmp, y_bytes, hipMemcpyDeviceToDevice, stream);
  }
}

// Round 3
// 319.397 us; speedup vs baseline: 1.5103x; 1.5103x over previous
//
#include <hip/hip_runtime.h>

#define Bb 4
#define Tt 2048
#define Cc 1024
#define Hh 16
#define NQKV 3072
#define Mtot 8192

typedef __bf16 bf16_t;
typedef unsigned short u16;
typedef __bf16 bf16x8 __attribute__((ext_vector_type(8)));
typedef float f32x4 __attribute__((ext_vector_type(4)));

union bfu { bf16_t b; u16 u; };
union v16 { uint4 q; u16 s[8]; };

// ---------------------------------------------------------------------------
// f32 -> bf16 conversion (8 elems/thread, exact grid)
// ---------------------------------------------------------------------------
__global__ __launch_bounds__(256) void cvt_f32_bf16(const float* __restrict__ s,
                                                    u16* __restrict__ d) {
  size_t i = ((size_t)blockIdx.x * 256 + threadIdx.x) * 8;
  float4 a = *(const float4*)(s + i);
  float4 b = *(const float4*)(s + i + 4);
  bf16x8 v;
  v[0]=(bf16_t)a.x; v[1]=(bf16_t)a.y; v[2]=(bf16_t)a.z; v[3]=(bf16_t)a.w;
  v[4]=(bf16_t)b.x; v[5]=(bf16_t)b.y; v[6]=(bf16_t)b.z; v[7]=(bf16_t)b.w;
  *(bf16x8*)(d + i) = v;
}

// ---------------------------------------------------------------------------
// GEMM NT, bf16 inputs: out[m][n] = sum_k A[m][k]*B[n][k] + bias[n]
// 128x128 tile, BK=32, 4 waves (2x2), 64x64/wave. Reg-staged with preload.
// ---------------------------------------------------------------------------
template <int OUTBF16>
__global__ __launch_bounds__(256) void gemm_bf16(
    const u16* __restrict__ A, const u16* __restrict__ Bm,
    const float* __restrict__ bias, void* __restrict__ Cout,
    int M, int N, int K)
{
  __shared__ __attribute__((aligned(16))) u16 sa[128][40];
  __shared__ __attribute__((aligned(16))) u16 sb[128][40];

  const int tid  = threadIdx.x;
  const int lane = tid & 63;
  const int wid  = tid >> 6;
  const int wr   = (wid >> 1) * 64;
  const int wc   = (wid & 1) * 64;
  const int l15  = lane & 15;
  const int lh   = lane >> 4;
  const int bm   = blockIdx.x * 128;
  const int bn   = blockIdx.y * 128;

  f32x4 acc[4][4] = {};

  const int srow = tid >> 1;          // 0..127
  const int sseg = (tid & 1) * 16;    // 0,16

  const u16* pa = A  + (size_t)(bm + srow) * K + sseg;
  const u16* pb = Bm + (size_t)(bn + srow) * K + sseg;

  uint4 ar0 = *(const uint4*)pa, ar1 = *(const uint4*)(pa + 8);
  uint4 br0 = *(const uint4*)pb, br1 = *(const uint4*)(pb + 8);
  pa += 32; pb += 32;

  for (int k0 = 0; k0 < K; k0 += 32) {
    __syncthreads();
    *(uint4*)&sa[srow][sseg]     = ar0;
    *(uint4*)&sa[srow][sseg + 8] = ar1;
    *(uint4*)&sb[srow][sseg]     = br0;
    *(uint4*)&sb[srow][sseg + 8] = br1;
    __syncthreads();
    if (k0 + 32 < K) {
      ar0 = *(const uint4*)pa; ar1 = *(const uint4*)(pa + 8);
      br0 = *(const uint4*)pb; br1 = *(const uint4*)(pb + 8);
      pa += 32; pb += 32;
    }
    bf16x8 af[4], bfv[4];
#pragma unroll
    for (int mi = 0; mi < 4; mi++)
      af[mi] = *(const bf16x8*)&sa[wr + mi*16 + l15][lh * 8];
#pragma unroll
    for (int ni = 0; ni < 4; ni++)
      bfv[ni] = *(const bf16x8*)&sb[wc + ni*16 + l15][lh * 8];
#pragma unroll
    for (int mi = 0; mi < 4; mi++)
#pragma unroll
      for (int ni = 0; ni < 4; ni++)
        acc[mi][ni] = __builtin_amdgcn_mfma_f32_16x16x32_bf16(
            af[mi], bfv[ni], acc[mi][ni], 0, 0, 0);
  }

#pragma unroll
  for (int mi = 0; mi < 4; mi++) {
#pragma unroll
    for (int ni = 0; ni < 4; ni++) {
      const int col = bn + wc + ni*16 + l15;
      const float bs = bias[col];
#pragma unroll
      for (int r = 0; r < 4; r++) {
        const int row = bm + wr + mi*16 + lh*4 + r;
        const float val = acc[mi][ni][r] + bs;
        if (OUTBF16) {
          bfu cv; cv.b = (bf16_t)val;
          ((u16*)Cout)[(size_t)row * N + col] = cv.u;
        } else {
          ((float*)Cout)[(size_t)row * N + col] = val;
        }
      }
    }
  }
}

// ---------------------------------------------------------------------------
// Causal flash attention, bf16 qkv in, bf16 y out. No inline asm.
// Block: 256 thr / 4 waves; 128 q rows/block (32/wave, 2 frags of 16).
// LDS (u16 idx): K [0,4608) as [64key][72d-pad]
//                V^T [4608,9248) as [4 dgrp (stride 1160)][16 d (stride 72)][64 key]
//                P [9248,18464) per-wave [32 q][72 key-pad]
// ---------------------------------------------------------------------------
#define VT0 4608
#define PT0 9248
__global__ __launch_bounds__(256) void attn_kernel(
    const u16* __restrict__ qkv, u16* __restrict__ y)
{
  __shared__ __attribute__((aligned(16))) u16 smem[18464];

  const int tid  = threadIdx.x;
  const int lane = tid & 63;
  const int w    = tid >> 6;
  const int l15  = lane & 15;
  const int lh   = lane >> 4;
  const int qb   = 15 - blockIdx.x;      // longest blocks launch first
  const int qbase = qb * 128;
  const int bh   = blockIdx.y;
  const int b    = bh >> 4;
  const int h    = bh & 15;
  const int qw   = qbase + w * 32;       // wave's first q row

  const size_t rowbase = (size_t)b * Tt * NQKV;

  // Q fragments (A operand), scale 1/sqrt(64) folded in
  bf16x8 qA[2][2];
#pragma unroll
  for (int qf = 0; qf < 2; ++qf)
#pragma unroll
    for (int kd = 0; kd < 2; ++kd) {
      bf16x8 v = *(const bf16x8*)(qkv + rowbase +
                   (size_t)(qw + qf*16 + l15) * NQKV + h*64 + kd*32 + lh*8);
#pragma unroll
      for (int i = 0; i < 8; i++) v[i] = (bf16_t)((float)v[i] * 0.125f);
      qA[qf][kd] = v;
    }

  f32x4 o[2][4] = {};
  float m_run[2][4], l_run[2][4];
#pragma unroll
  for (int qf = 0; qf < 2; ++qf)
#pragma unroll
    for (int r = 0; r < 4; ++r) { m_run[qf][r] = -1e30f; l_run[qf][r] = 0.0f; }

  const int ktiles = 2*qb + 2;

  // staging map: 32B of one key row per thread (K and V)
  const int skey = tid >> 2;
  const int sp   = tid & 3;
  const u16* kbase = qkv + rowbase + 1024 + h*64 + sp*16;
  const u16* vbase = qkv + rowbase + 2048 + h*64 + sp*16;

  uint4 kr0 = *(const uint4*)(kbase + (size_t)skey * NQKV);
  uint4 kr1 = *(const uint4*)(kbase + (size_t)skey * NQKV + 8);
  uint4 vr0 = *(const uint4*)(vbase + (size_t)skey * NQKV);
  uint4 vr1 = *(const uint4*)(vbase + (size_t)skey * NQKV + 8);

  for (int kt = 0; kt < ktiles; ++kt) {
    __syncthreads();
    // K tile [key][72]: vectorized
    *(uint4*)&smem[skey*72 + sp*16]     = kr0;
    *(uint4*)&smem[skey*72 + sp*16 + 8] = kr1;
    // V^T tile: scalar transpose writes (dgrp pad -> ~2-way conflicts)
    {
      v16 a, bb; a.q = vr0; bb.q = vr1;
      const int base = VT0 + sp*1160 + skey;
#pragma unroll
      for (int i = 0; i < 8; i++) smem[base + i*72]       = a.s[i];
#pragma unroll
      for (int i = 0; i < 8; i++) smem[base + (i+8)*72]   = bb.s[i];
    }
    __syncthreads();

    if (kt + 1 < ktiles) {  // T14: issue next tile's loads before compute
      const u16* kp = kbase + (size_t)((kt+1)*64 + skey) * NQKV;
      const u16* vp = vbase + (size_t)((kt+1)*64 + skey) * NQKV;
      kr0 = *(const uint4*)kp; kr1 = *(const uint4*)(kp + 8);
      vr0 = *(const uint4*)vp; vr1 = *(const uint4*)(vp + 8);
    }

    if (kt*64 <= qw + 31) {   // wave has unmasked work in this tile
      // ---- S = Q K^T ----
      f32x4 s[2][4] = {};
#pragma unroll
      for (int fc = 0; fc < 4; ++fc)
#pragma unroll
        for (int kd = 0; kd < 2; ++kd) {
          bf16x8 kf = *(const bf16x8*)&smem[(fc*16 + l15)*72 + kd*32 + lh*8];
          s[0][fc] = __builtin_amdgcn_mfma_f32_16x16x32_bf16(qA[0][kd], kf, s[0][fc], 0,0,0);
          s[1][fc] = __builtin_amdgcn_mfma_f32_16x16x32_bf16(qA[1][kd], kf, s[1][fc], 0,0,0);
        }

      // ---- causal mask ----
      if (kt*64 + 63 > qw) {
#pragma unroll
        for (int qf = 0; qf < 2; ++qf)
#pragma unroll
          for (int fc = 0; fc < 4; ++fc) {
            const int key = kt*64 + fc*16 + l15;
#pragma unroll
            for (int r = 0; r < 4; ++r) {
              const int q = qw + qf*16 + lh*4 + r;
              if (key > q) s[qf][fc][r] = -1e30f;
            }
          }
      }

      // ---- online softmax (rows on l15-groups), defer-max THR=8 ----
#pragma unroll
      for (int qf = 0; qf < 2; ++qf) {
        float rm[4];
#pragma unroll
        for (int r = 0; r < 4; ++r)
          rm[r] = fmaxf(fmaxf(s[qf][0][r], s[qf][1][r]),
                        fmaxf(s[qf][2][r], s[qf][3][r]));
#pragma unroll
        for (int msk = 1; msk < 16; msk <<= 1)
#pragma unroll
          for (int r = 0; r < 4; ++r)
            rm[r] = fmaxf(rm[r], __shfl_xor(rm[r], msk));

        int need = 0;
#pragma unroll
        for (int r = 0; r < 4; ++r) need |= (rm[r] > m_run[qf][r] + 8.0f);
        if (__any(need)) {
#pragma unroll
          for (int r = 0; r < 4; ++r) {
            const float mn = fmaxf(m_run[qf][r], rm[r]);
            const float al = __expf(m_run[qf][r] - mn);
            m_run[qf][r] = mn;
            l_run[qf][r] *= al;
#pragma unroll
            for (int fd = 0; fd < 4; ++fd) o[qf][fd][r] *= al;
          }
        }

        float rs[4] = {0.f, 0.f, 0.f, 0.f};
#pragma unroll
        for (int fc = 0; fc < 4; ++fc)
#pragma unroll
          for (int r = 0; r < 4; ++r) {
            const float p = __expf(s[qf][fc][r] - m_run[qf][r]);
            rs[r] += p;
            bfu cv; cv.b = (bf16_t)p;
            // P [q][key] per wave, scalar write (round-1-proven layout)
            smem[PT0 + w*2304 + (qf*16 + lh*4 + r)*72 + fc*16 + l15] = cv.u;
          }
#pragma unroll
        for (int msk = 1; msk < 16; msk <<= 1)
#pragma unroll
          for (int r = 0; r < 4; ++r) rs[r] += __shfl_xor(rs[r], msk);
#pragma unroll
        for (int r = 0; r < 4; ++r) l_run[qf][r] += rs[r];
      }

      // ---- O += P V  (all contiguous b128 reads; compiler-ordered) ----
#pragma unroll
      for (int ka = 0; ka < 2; ++ka) {
        bf16x8 pa0 = *(const bf16x8*)&smem[PT0 + w*2304 + (0*16 + l15)*72 + ka*32 + lh*8];
        bf16x8 pa1 = *(const bf16x8*)&smem[PT0 + w*2304 + (1*16 + l15)*72 + ka*32 + lh*8];
#pragma unroll
        for (int fd = 0; fd < 4; ++fd) {
          bf16x8 vf = *(const bf16x8*)&smem[VT0 + fd*1160 + l15*72 + ka*32 + lh*8];
          o[0][fd] = __builtin_amdgcn_mfma_f32_16x16x32_bf16(pa0, vf, o[0][fd], 0,0,0);
          o[1][fd] = __builtin_amdgcn_mfma_f32_16x16x32_bf16(pa1, vf, o[1][fd], 0,0,0);
        }
      }
    }
  }

  // ---- epilogue: normalize, transpose via LDS (per-wave region), store ----
  __syncthreads();   // everyone done with K/V regions
#pragma unroll
  for (int qf = 0; qf < 2; ++qf)
#pragma unroll
    for (int fd = 0; fd < 4; ++fd)
#pragma unroll
      for (int r = 0; r < 4; ++r) {
        bfu cv; cv.b = (bf16_t)(o[qf][fd][r] / l_run[qf][r]);
        smem[w*2304 + (qf*16 + lh*4 + r)*72 + fd*16 + l15] = cv.u;
      }
#pragma unroll
  for (int qf = 0; qf < 2; ++qf) {
    const int rw = qf*16 + l15;
    const int t  = qbase + w*32 + rw;
    u16* yp = y + ((size_t)(b*Tt + t))*Cc + h*64 + lh*16;
    uint4 v0 = *(uint4*)&smem[w*2304 + rw*72 + lh*16];
    uint4 v1 = *(uint4*)&smem[w*2304 + rw*72 + lh*16 + 8];
    *(uint4*)yp = v0;
    *(uint4*)(yp + 8) = v1;
  }
}

// ---------------------------------------------------------------------------
extern "C" void kernel_launch(void* const* d_in, const int* in_sizes, int n_in,
                              void* d_out, int out_size, void* d_ws, size_t ws_size,
                              hipStream_t stream) {
  const float* x      = (const float*)d_in[0];
  const float* w_attn = (const float*)d_in[1];
  const float* b_attn = (const float*)d_in[2];
  const float* w_proj = (const float*)d_in[3];
  const float* b_proj = (const float*)d_in[4];
  float* out = (float*)d_out;

  char* ws = (char*)d_ws;
  u16* xb   = (u16*)(ws + 0);          // 16 MB
  u16* wab  = (u16*)(ws + 16777216);   // 6 MB
  u16* wpb  = (u16*)(ws + 23068672);   // 2 MB
  u16* qkvb = (u16*)(ws + 25165824);   // 48 MB
  u16* yb   = (u16*)(ws + 75497472);   // 16 MB  (end 92274688)

  // convert inputs to bf16
  cvt_f32_bf16<<<4096, 256, 0, stream>>>(x,      xb);
  cvt_f32_bf16<<<1536, 256, 0, stream>>>(w_attn, wab);
  cvt_f32_bf16<<<512,  256, 0, stream>>>(w_proj, wpb);

  // 1) QKV projection (bf16 out)
  gemm_bf16<1><<<dim3(Mtot/128, NQKV/128), 256, 0, stream>>>(
      xb, wab, b_attn, (void*)qkvb, Mtot, NQKV, Cc);

  // 2) causal attention (bf16 y)
  attn_kernel<<<dim3(16, Bb*Hh), 256, 0, stream>>>(qkvb, yb);

  // 3) output projection (f32 out)
  gemm_bf16<0><<<dim3(Mtot/128, Cc/128), 256, 0, stream>>>(
      yb, wpb, b_proj, (void*)out, Mtot, Cc, Cc);
}

// Round 4
// 197.214 us; speedup vs baseline: 2.4460x; 1.6195x over previous
//
#include <hip/hip_runtime.h>

#define Bb 4
#define Tt 2048
#define Cc 1024
#define Hh 16
#define NQKV 3072
#define Mtot 8192

typedef __bf16 bf16_t;
typedef unsigned short u16;
typedef __bf16 bf16x8 __attribute__((ext_vector_type(8)));
typedef __bf16 bf16x4 __attribute__((ext_vector_type(4)));
typedef short short4v __attribute__((ext_vector_type(4)));
typedef float f32x4 __attribute__((ext_vector_type(4)));

union bfu { bf16_t b; u16 u; };
union trpair { short4v h[2]; bf16x8 v; };

// hardware transpose read; "memory" clobber keeps it ordered after P ds_writes
#define TRD(dst, addr, OFF)                                                     \
  asm volatile("ds_read_b64_tr_b16 %0, %1 offset:" OFF                          \
               : "=v"(dst) : "v"(addr) : "memory")

// DPP cross-lane reduce within 16-lane rows (VALU pipe, not LDS)
#define DPPF(x, CTRL) __int_as_float(                                           \
    __builtin_amdgcn_mov_dpp(__float_as_int(x), CTRL, 0xf, 0xf, true))
__device__ __forceinline__ float rowmax16(float v) {
  v = fmaxf(v, DPPF(v, 0xB1));   // quad_perm [1,0,3,2]  (xor 1)
  v = fmaxf(v, DPPF(v, 0x4E));   // quad_perm [2,3,0,1]  (xor 2)
  v = fmaxf(v, DPPF(v, 0x124));  // row_ror:4
  v = fmaxf(v, DPPF(v, 0x128));  // row_ror:8
  return v;
}
__device__ __forceinline__ float rowsum16(float v) {
  v = v + DPPF(v, 0xB1);
  v = v + DPPF(v, 0x4E);
  v = v + DPPF(v, 0x124);
  v = v + DPPF(v, 0x128);
  return v;
}

// ---------------------------------------------------------------------------
// f32 -> bf16 conversion (8 elems/thread, exact grid)
// ---------------------------------------------------------------------------
__global__ __launch_bounds__(256) void cvt_f32_bf16(const float* __restrict__ s,
                                                    u16* __restrict__ d) {
  size_t i = ((size_t)blockIdx.x * 256 + threadIdx.x) * 8;
  float4 a = *(const float4*)(s + i);
  float4 b = *(const float4*)(s + i + 4);
  bf16x8 v;
  v[0]=(bf16_t)a.x; v[1]=(bf16_t)a.y; v[2]=(bf16_t)a.z; v[3]=(bf16_t)a.w;
  v[4]=(bf16_t)b.x; v[5]=(bf16_t)b.y; v[6]=(bf16_t)b.z; v[7]=(bf16_t)b.w;
  *(bf16x8*)(d + i) = v;
}

// ---------------------------------------------------------------------------
// GEMM NT, bf16 inputs (unchanged from round 3 — ~892 TF combined)
// ---------------------------------------------------------------------------
template <int OUTBF16>
__global__ __launch_bounds__(256) void gemm_bf16(
    const u16* __restrict__ A, const u16* __restrict__ Bm,
    const float* __restrict__ bias, void* __restrict__ Cout,
    int M, int N, int K)
{
  __shared__ __attribute__((aligned(16))) u16 sa[128][40];
  __shared__ __attribute__((aligned(16))) u16 sb[128][40];

  const int tid  = threadIdx.x;
  const int lane = tid & 63;
  const int wid  = tid >> 6;
  const int wr   = (wid >> 1) * 64;
  const int wc   = (wid & 1) * 64;
  const int l15  = lane & 15;
  const int lh   = lane >> 4;
  const int bm   = blockIdx.x * 128;
  const int bn   = blockIdx.y * 128;

  f32x4 acc[4][4] = {};

  const int srow = tid >> 1;
  const int sseg = (tid & 1) * 16;

  const u16* pa = A  + (size_t)(bm + srow) * K + sseg;
  const u16* pb = Bm + (size_t)(bn + srow) * K + sseg;

  uint4 ar0 = *(const uint4*)pa, ar1 = *(const uint4*)(pa + 8);
  uint4 br0 = *(const uint4*)pb, br1 = *(const uint4*)(pb + 8);
  pa += 32; pb += 32;

  for (int k0 = 0; k0 < K; k0 += 32) {
    __syncthreads();
    *(uint4*)&sa[srow][sseg]     = ar0;
    *(uint4*)&sa[srow][sseg + 8] = ar1;
    *(uint4*)&sb[srow][sseg]     = br0;
    *(uint4*)&sb[srow][sseg + 8] = br1;
    __syncthreads();
    if (k0 + 32 < K) {
      ar0 = *(const uint4*)pa; ar1 = *(const uint4*)(pa + 8);
      br0 = *(const uint4*)pb; br1 = *(const uint4*)(pb + 8);
      pa += 32; pb += 32;
    }
    bf16x8 af[4], bfv[4];
#pragma unroll
    for (int mi = 0; mi < 4; mi++)
      af[mi] = *(const bf16x8*)&sa[wr + mi*16 + l15][lh * 8];
#pragma unroll
    for (int ni = 0; ni < 4; ni++)
      bfv[ni] = *(const bf16x8*)&sb[wc + ni*16 + l15][lh * 8];
#pragma unroll
    for (int mi = 0; mi < 4; mi++)
#pragma unroll
      for (int ni = 0; ni < 4; ni++)
        acc[mi][ni] = __builtin_amdgcn_mfma_f32_16x16x32_bf16(
            af[mi], bfv[ni], acc[mi][ni], 0, 0, 0);
  }

#pragma unroll
  for (int mi = 0; mi < 4; mi++) {
#pragma unroll
    for (int ni = 0; ni < 4; ni++) {
      const int col = bn + wc + ni*16 + l15;
      const float bs = bias[col];
#pragma unroll
      for (int r = 0; r < 4; r++) {
        const int row = bm + wr + mi*16 + lh*4 + r;
        const float val = acc[mi][ni][r] + bs;
        if (OUTBF16) {
          bfu cv; cv.b = (bf16_t)val;
          ((u16*)Cout)[(size_t)row * N + col] = cv.u;
        } else {
          ((float*)Cout)[(size_t)row * N + col] = val;
        }
      }
    }
  }
}

// ---------------------------------------------------------------------------
// Causal flash attention, bf16 qkv in, bf16 y out.
// Grid (8, B*H): block handles q-tile pair {x, 15-x} (uniform 34 k-tiles).
// LDS (u16 idx): K [0,4608)      as [64 key][72 d-pad]
//                V [4608,9728)   as [64 key][80 d-pad]  (row-major!)
//                P^T [9728,17920) per (wave,qf) panel [64 key][16 q]
// V and P consumed as MFMA B/A fragments via ds_read_b64_tr_b16.
// ---------------------------------------------------------------------------
#define VT0 4608
#define PT0 9728
__global__ __launch_bounds__(256) void attn_kernel(
    const u16* __restrict__ qkv, u16* __restrict__ y)
{
  __shared__ __attribute__((aligned(16))) u16 smem[17920];

  const int tid  = threadIdx.x;
  const int lane = tid & 63;
  const int w    = tid >> 6;
  const int l15  = lane & 15;
  const int lh   = lane >> 4;
  const int bh   = blockIdx.y;
  const int b    = bh >> 4;
  const int h    = bh & 15;

  const size_t rowbase = (size_t)b * Tt * NQKV;

  // staging map: 32B of one key row per thread (K and V, identical pattern)
  const int skey = tid >> 2;
  const int sp   = tid & 3;
  const u16* kbase = qkv + rowbase + 1024 + h*64 + sp*16;
  const u16* vbase = qkv + rowbase + 2048 + h*64 + sp*16;

  // transpose-read lane addresses (bytes)
  const unsigned smemB = (unsigned)(size_t)(&smem[0]);
  const unsigned vaddr = smemB + 9216  + (lh*8 + (l15>>2))*160 + (l15&3)*8;
  const unsigned paddr = smemB + 19456 + w*4096 + (lh*8 + (l15>>2))*32 + (l15&3)*8;

  for (int half = 0; half < 2; ++half) {
    const int qb    = half ? (15 - blockIdx.x) : blockIdx.x;
    const int qbase = qb * 128;
    const int qw    = qbase + w * 32;
    const int ktiles = 2*qb + 2;

    // Q fragments (A operand), scale 1/sqrt(64) folded in
    bf16x8 qA[2][2];
#pragma unroll
    for (int qf = 0; qf < 2; ++qf)
#pragma unroll
      for (int kd = 0; kd < 2; ++kd) {
        bf16x8 v = *(const bf16x8*)(qkv + rowbase +
                     (size_t)(qw + qf*16 + l15) * NQKV + h*64 + kd*32 + lh*8);
#pragma unroll
        for (int i = 0; i < 8; i++) v[i] = (bf16_t)((float)v[i] * 0.125f);
        qA[qf][kd] = v;
      }

    f32x4 o[2][4] = {};
    float m_run[2][4], l_part[2][4];
#pragma unroll
    for (int qf = 0; qf < 2; ++qf)
#pragma unroll
      for (int r = 0; r < 4; ++r) { m_run[qf][r] = -1e30f; l_part[qf][r] = 0.0f; }

    uint4 kr0 = *(const uint4*)(kbase + (size_t)skey * NQKV);
    uint4 kr1 = *(const uint4*)(kbase + (size_t)skey * NQKV + 8);
    uint4 vr0 = *(const uint4*)(vbase + (size_t)skey * NQKV);
    uint4 vr1 = *(const uint4*)(vbase + (size_t)skey * NQKV + 8);

    for (int kt = 0; kt < ktiles; ++kt) {
      __syncthreads();
      *(uint4*)&smem[skey*72 + sp*16]           = kr0;
      *(uint4*)&smem[skey*72 + sp*16 + 8]       = kr1;
      *(uint4*)&smem[VT0 + skey*80 + sp*16]     = vr0;
      *(uint4*)&smem[VT0 + skey*80 + sp*16 + 8] = vr1;
      __syncthreads();

      if (kt + 1 < ktiles) {  // T14: issue next tile's loads before compute
        const u16* kp = kbase + (size_t)((kt+1)*64 + skey) * NQKV;
        const u16* vp = vbase + (size_t)((kt+1)*64 + skey) * NQKV;
        kr0 = *(const uint4*)kp; kr1 = *(const uint4*)(kp + 8);
        vr0 = *(const uint4*)vp; vr1 = *(const uint4*)(vp + 8);
      }

      if (kt*64 <= qw + 31) {   // wave has unmasked work in this tile
        // ---- S = Q K^T ----
        f32x4 s[2][4] = {};
#pragma unroll
        for (int fc = 0; fc < 4; ++fc)
#pragma unroll
          for (int kd = 0; kd < 2; ++kd) {
            bf16x8 kf = *(const bf16x8*)&smem[(fc*16 + l15)*72 + kd*32 + lh*8];
            s[0][fc] = __builtin_amdgcn_mfma_f32_16x16x32_bf16(qA[0][kd], kf, s[0][fc], 0,0,0);
            s[1][fc] = __builtin_amdgcn_mfma_f32_16x16x32_bf16(qA[1][kd], kf, s[1][fc], 0,0,0);
          }

        // ---- causal mask (diagonal tiles only) ----
        if (kt*64 + 63 > qw) {
#pragma unroll
          for (int qf = 0; qf < 2; ++qf)
#pragma unroll
            for (int fc = 0; fc < 4; ++fc) {
              const int key = kt*64 + fc*16 + l15;
#pragma unroll
              for (int r = 0; r < 4; ++r) {
                const int q = qw + qf*16 + lh*4 + r;
                if (key > q) s[qf][fc][r] = -1e30f;
              }
            }
        }

        // ---- online softmax: DPP row-max, defer-max THR=8, lane-partial l ----
#pragma unroll
        for (int qf = 0; qf < 2; ++qf) {
          float rm[4];
#pragma unroll
          for (int r = 0; r < 4; ++r) {
            rm[r] = fmaxf(fmaxf(s[qf][0][r], s[qf][1][r]),
                          fmaxf(s[qf][2][r], s[qf][3][r]));
            rm[r] = rowmax16(rm[r]);
          }
          int need = 0;
#pragma unroll
          for (int r = 0; r < 4; ++r) need |= (rm[r] > m_run[qf][r] + 8.0f);
          if (__any(need)) {
#pragma unroll
            for (int r = 0; r < 4; ++r) {
              const float mn = fmaxf(m_run[qf][r], rm[r]);
              const float al = __expf(m_run[qf][r] - mn);
              m_run[qf][r] = mn;
              l_part[qf][r] *= al;
#pragma unroll
              for (int fd = 0; fd < 4; ++fd) o[qf][fd][r] *= al;
            }
          }
#pragma unroll
          for (int fc = 0; fc < 4; ++fc) {
            bf16x4 pk;
#pragma unroll
            for (int r = 0; r < 4; ++r) {
              const float p = __expf(s[qf][fc][r] - m_run[qf][r]);
              l_part[qf][r] += p;
              pk[r] = (bf16_t)p;
            }
            // P^T panel [key][16 q]: one 8B write per fc
            *(bf16x4*)&smem[PT0 + (w*2+qf)*1024 + (fc*16 + l15)*16 + lh*4] = pk;
          }
        }

        // ---- O += P V via transpose-reads ----
        asm volatile("s_waitcnt lgkmcnt(0)" ::: "memory");  // P writes drained
#pragma unroll
        for (int kd = 0; kd < 2; ++kd) {
          short4v tv0,tv1,tv2,tv3,tv4,tv5,tv6,tv7, tp0,tp1,tp2,tp3;
          if (kd == 0) {
            TRD(tv0, vaddr, "0");    TRD(tv1, vaddr, "640");
            TRD(tv2, vaddr, "32");   TRD(tv3, vaddr, "672");
            TRD(tv4, vaddr, "64");   TRD(tv5, vaddr, "704");
            TRD(tv6, vaddr, "96");   TRD(tv7, vaddr, "736");
            TRD(tp0, paddr, "0");    TRD(tp1, paddr, "128");
            TRD(tp2, paddr, "2048"); TRD(tp3, paddr, "2176");
          } else {
            TRD(tv0, vaddr, "5120"); TRD(tv1, vaddr, "5760");
            TRD(tv2, vaddr, "5152"); TRD(tv3, vaddr, "5792");
            TRD(tv4, vaddr, "5184"); TRD(tv5, vaddr, "5824");
            TRD(tv6, vaddr, "5216"); TRD(tv7, vaddr, "5856");
            TRD(tp0, paddr, "1024"); TRD(tp1, paddr, "1152");
            TRD(tp2, paddr, "3072"); TRD(tp3, paddr, "3200");
          }
          asm volatile("s_waitcnt lgkmcnt(0)" ::: "memory");
          __builtin_amdgcn_sched_barrier(0);
          trpair vb0, vb1, vb2, vb3, pa0, pa1;
          vb0.h[0]=tv0; vb0.h[1]=tv1;  vb1.h[0]=tv2; vb1.h[1]=tv3;
          vb2.h[0]=tv4; vb2.h[1]=tv5;  vb3.h[0]=tv6; vb3.h[1]=tv7;
          pa0.h[0]=tp0; pa0.h[1]=tp1;  pa1.h[0]=tp2; pa1.h[1]=tp3;
          o[0][0] = __builtin_amdgcn_mfma_f32_16x16x32_bf16(pa0.v, vb0.v, o[0][0], 0,0,0);
          o[0][1] = __builtin_amdgcn_mfma_f32_16x16x32_bf16(pa0.v, vb1.v, o[0][1], 0,0,0);
          o[0][2] = __builtin_amdgcn_mfma_f32_16x16x32_bf16(pa0.v, vb2.v, o[0][2], 0,0,0);
          o[0][3] = __builtin_amdgcn_mfma_f32_16x16x32_bf16(pa0.v, vb3.v, o[0][3], 0,0,0);
          o[1][0] = __builtin_amdgcn_mfma_f32_16x16x32_bf16(pa1.v, vb0.v, o[1][0], 0,0,0);
          o[1][1] = __builtin_amdgcn_mfma_f32_16x16x32_bf16(pa1.v, vb1.v, o[1][1], 0,0,0);
          o[1][2] = __builtin_amdgcn_mfma_f32_16x16x32_bf16(pa1.v, vb2.v, o[1][2], 0,0,0);
          o[1][3] = __builtin_amdgcn_mfma_f32_16x16x32_bf16(pa1.v, vb3.v, o[1][3], 0,0,0);
        }
      }
    }

    // ---- epilogue: reduce l, normalize, transpose via LDS, store ----
    float lsum[2][4];
#pragma unroll
    for (int qf = 0; qf < 2; ++qf)
#pragma unroll
      for (int r = 0; r < 4; ++r) lsum[qf][r] = rowsum16(l_part[qf][r]);

    __syncthreads();   // everyone done with K/V regions
#pragma unroll
    for (int qf = 0; qf < 2; ++qf)
#pragma unroll
      for (int fd = 0; fd < 4; ++fd)
#pragma unroll
        for (int r = 0; r < 4; ++r) {
          bfu cv; cv.b = (bf16_t)(o[qf][fd][r] / lsum[qf][r]);
          smem[w*2304 + (qf*16 + lh*4 + r)*72 + fd*16 + l15] = cv.u;
        }
#pragma unroll
    for (int qf = 0; qf < 2; ++qf) {
      const int rw = qf*16 + l15;
      const int t  = qbase + w*32 + rw;
      u16* yp = y + ((size_t)(b*Tt + t))*Cc + h*64 + lh*16;
      uint4 v0 = *(uint4*)&smem[w*2304 + rw*72 + lh*16];
      uint4 v1 = *(uint4*)&smem[w*2304 + rw*72 + lh*16 + 8];
      *(uint4*)yp = v0;
      *(uint4*)(yp + 8) = v1;
    }
    // loop-top __syncthreads of next half orders epilogue reads vs restaging
  }
}

// ---------------------------------------------------------------------------
extern "C" void kernel_launch(void* const* d_in, const int* in_sizes, int n_in,
                              void* d_out, int out_size, void* d_ws, size_t ws_size,
                              hipStream_t stream) {
  const float* x      = (const float*)d_in[0];
  const float* w_attn = (const float*)d_in[1];
  const float* b_attn = (const float*)d_in[2];
  const float* w_proj = (const float*)d_in[3];
  const float* b_proj = (const float*)d_in[4];
  float* out = (float*)d_out;

  char* ws = (char*)d_ws;
  u16* xb   = (u16*)(ws + 0);          // 16 MB
  u16* wab  = (u16*)(ws + 16777216);   // 6 MB
  u16* wpb  = (u16*)(ws + 23068672);   // 2 MB
  u16* qkvb = (u16*)(ws + 25165824);   // 48 MB
  u16* yb   = (u16*)(ws + 75497472);   // 16 MB

  cvt_f32_bf16<<<4096, 256, 0, stream>>>(x,      xb);
  cvt_f32_bf16<<<1536, 256, 0, stream>>>(w_attn, wab);
  cvt_f32_bf16<<<512,  256, 0, stream>>>(w_proj, wpb);

  gemm_bf16<1><<<dim3(Mtot/128, NQKV/128), 256, 0, stream>>>(
      xb, wab, b_attn, (void*)qkvb, Mtot, NQKV, Cc);

  attn_kernel<<<dim3(8, Bb*Hh), 256, 0, stream>>>(qkvb, yb);

  gemm_bf16<0><<<dim3(Mtot/128, Cc/128), 256, 0, stream>>>(
      yb, wpb, b_proj, (void*)out, Mtot, Cc, Cc);
}

// Round 5
// 192.270 us; speedup vs baseline: 2.5089x; 1.0257x over previous
//
#include <hip/hip_runtime.h>

#define Bb 4
#define Tt 2048
#define Cc 1024
#define Hh 16
#define NQKV 3072
#define Mtot 8192

typedef __bf16 bf16_t;
typedef unsigned short u16;
typedef __bf16 bf16x8 __attribute__((ext_vector_type(8)));
typedef __bf16 bf16x4 __attribute__((ext_vector_type(4)));
typedef short short4v __attribute__((ext_vector_type(4)));
typedef float f32x4 __attribute__((ext_vector_type(4)));
typedef float f32x16 __attribute__((ext_vector_type(16)));
typedef unsigned uint2v __attribute__((ext_vector_type(2)));

union bfu { bf16_t b; u16 u; };
union trpair { short4v h[2]; bf16x8 v; };
union pfu { unsigned u[4]; bf16x8 v; };

#define QSCALE 0.18033688011112042f  /* 0.125 * log2(e) */

// hardware transpose read; "memory" clobber keeps it ordered after staging
#define TRD(dst, addr, OFF)                                                     \
  asm volatile("ds_read_b64_tr_b16 %0, %1 offset:" OFF                          \
               : "=v"(dst) : "v"(addr) : "memory")

__device__ __forceinline__ unsigned cvtpk(float a, float b) {
  unsigned r;
  asm("v_cvt_pk_bf16_f32 %0, %1, %2" : "=v"(r) : "v"(a), "v"(b));
  return r;
}
__device__ __forceinline__ uint2v plswap(unsigned a, unsigned b) {
  return __builtin_amdgcn_permlane32_swap(a, b, false, false);
}

// ---------------------------------------------------------------------------
// f32 -> bf16 conversion; elements with idx < nscale multiplied by factor
// ---------------------------------------------------------------------------
__global__ __launch_bounds__(256) void cvt_f32_bf16(const float* __restrict__ s,
                                                    u16* __restrict__ d,
                                                    long nscale, float factor) {
  size_t i = ((size_t)blockIdx.x * 256 + threadIdx.x) * 8;
  const float f = ((long)i < nscale) ? factor : 1.0f;
  float4 a = *(const float4*)(s + i);
  float4 b = *(const float4*)(s + i + 4);
  bf16x8 v;
  v[0]=(bf16_t)(a.x*f); v[1]=(bf16_t)(a.y*f); v[2]=(bf16_t)(a.z*f); v[3]=(bf16_t)(a.w*f);
  v[4]=(bf16_t)(b.x*f); v[5]=(bf16_t)(b.y*f); v[6]=(bf16_t)(b.z*f); v[7]=(bf16_t)(b.w*f);
  *(bf16x8*)(d + i) = v;
}

__global__ __launch_bounds__(256) void scale_bias(const float* __restrict__ s,
                                                  float* __restrict__ d) {
  int i = blockIdx.x * 256 + threadIdx.x;  // 3072 total
  d[i] = s[i] * ((i < Cc) ? QSCALE : 1.0f);
}

// ---------------------------------------------------------------------------
// GEMM NT, bf16 inputs (unchanged round-3 structure)
// ---------------------------------------------------------------------------
template <int OUTBF16>
__global__ __launch_bounds__(256) void gemm_bf16(
    const u16* __restrict__ A, const u16* __restrict__ Bm,
    const float* __restrict__ bias, void* __restrict__ Cout,
    int M, int N, int K)
{
  __shared__ __attribute__((aligned(16))) u16 sa[128][40];
  __shared__ __attribute__((aligned(16))) u16 sb[128][40];

  const int tid  = threadIdx.x;
  const int lane = tid & 63;
  const int wid  = tid >> 6;
  const int wr   = (wid >> 1) * 64;
  const int wc   = (wid & 1) * 64;
  const int l15  = lane & 15;
  const int lh   = lane >> 4;
  const int bm   = blockIdx.x * 128;
  const int bn   = blockIdx.y * 128;

  f32x4 acc[4][4] = {};

  const int srow = tid >> 1;
  const int sseg = (tid & 1) * 16;

  const u16* pa = A  + (size_t)(bm + srow) * K + sseg;
  const u16* pb = Bm + (size_t)(bn + srow) * K + sseg;

  uint4 ar0 = *(const uint4*)pa, ar1 = *(const uint4*)(pa + 8);
  uint4 br0 = *(const uint4*)pb, br1 = *(const uint4*)(pb + 8);
  pa += 32; pb += 32;

  for (int k0 = 0; k0 < K; k0 += 32) {
    __syncthreads();
    *(uint4*)&sa[srow][sseg]     = ar0;
    *(uint4*)&sa[srow][sseg + 8] = ar1;
    *(uint4*)&sb[srow][sseg]     = br0;
    *(uint4*)&sb[srow][sseg + 8] = br1;
    __syncthreads();
    if (k0 + 32 < K) {
      ar0 = *(const uint4*)pa; ar1 = *(const uint4*)(pa + 8);
      br0 = *(const uint4*)pb; br1 = *(const uint4*)(pb + 8);
      pa += 32; pb += 32;
    }
    bf16x8 af[4], bfv[4];
#pragma unroll
    for (int mi = 0; mi < 4; mi++)
      af[mi] = *(const bf16x8*)&sa[wr + mi*16 + l15][lh * 8];
#pragma unroll
    for (int ni = 0; ni < 4; ni++)
      bfv[ni] = *(const bf16x8*)&sb[wc + ni*16 + l15][lh * 8];
#pragma unroll
    for (int mi = 0; mi < 4; mi++)
#pragma unroll
      for (int ni = 0; ni < 4; ni++)
        acc[mi][ni] = __builtin_amdgcn_mfma_f32_16x16x32_bf16(
            af[mi], bfv[ni], acc[mi][ni], 0, 0, 0);
  }

#pragma unroll
  for (int mi = 0; mi < 4; mi++) {
#pragma unroll
    for (int ni = 0; ni < 4; ni++) {
      const int col = bn + wc + ni*16 + l15;
      const float bs = bias[col];
#pragma unroll
      for (int r = 0; r < 4; r++) {
        const int row = bm + wr + mi*16 + lh*4 + r;
        const float val = acc[mi][ni][r] + bs;
        if (OUTBF16) {
          bfu cv; cv.b = (bf16_t)val;
          ((u16*)Cout)[(size_t)row * N + col] = cv.u;
        } else {
          ((float*)Cout)[(size_t)row * N + col] = val;
        }
      }
    }
  }
}

// ---------------------------------------------------------------------------
// Causal flash attention, T12 structure at 32x32 MFMA.
// Grid (8, B*H); block = 4 waves; wave owns 32 q rows; q-tile pair {x,15-x}.
// LDS (u16): K [0,4608) as [64 key][72 d-pad]; V [4608,9216) as [64 key][72].
// S^T = mfma(K,Q): q = lane&31, keys = (reg&3)+8*(reg>>2)+4*(lane>>5) (+32kb).
// Softmax per-lane scalar (m,l); P packed in-register (cvt_pk + permlane32).
// O^T = mfma(V^T via tr-reads, P).  Q prescaled by 0.125*log2e (in weights).
// ---------------------------------------------------------------------------
#define V0u 4608
__global__ __launch_bounds__(256) void attn_kernel(
    const u16* __restrict__ qkv, u16* __restrict__ y)
{
  __shared__ __attribute__((aligned(16))) u16 smem[9216];

  const int tid  = threadIdx.x;
  const int lane = tid & 63;
  const int w    = tid >> 6;
  const int l31  = lane & 31;
  const int hh   = lane >> 5;
  const int l15  = lane & 15;
  const int lh   = lane >> 4;
  const int bh   = blockIdx.y;
  const int b    = bh >> 4;
  const int head = bh & 15;

  const size_t rowbase = (size_t)b * Tt * NQKV;

  const int skey = tid >> 2;
  const int sp   = tid & 3;
  const u16* kbase = qkv + rowbase + 1024 + head*64 + sp*16;
  const u16* vbase = qkv + rowbase + 2048 + head*64 + sp*16;

  // V^T tr-read lane address (bytes): tile rows = keys, cols = d
  const unsigned smemB = (unsigned)(size_t)(&smem[0]);
  const unsigned vaddr = smemB + 2*V0u
      + ((lh>>1)*8 + (l15>>2))*144 + (lh&1)*32 + (l15&3)*8;

  for (int half = 0; half < 2; ++half) {
    const int qb    = half ? (15 - (int)blockIdx.x) : (int)blockIdx.x;
    const int qbase = qb * 128;
    const int qw    = qbase + w * 32;
    const int qi    = qw + l31;          // this lane's q row
    const int ktiles = 2*qb + 2;

    // Q fragments (B operand): lane holds Q[qi][m*16 + hh*8 + j]
    bf16x8 qfrag[4];
#pragma unroll
    for (int m = 0; m < 4; ++m)
      qfrag[m] = *(const bf16x8*)(qkv + rowbase + (size_t)qi * NQKV
                                  + head*64 + m*16 + hh*8);

    f32x16 o0 = {}, o1 = {};             // O^T: d2=0 (d 0..31), d2=1 (d 32..63)
    float m_run = -1e30f, l_part = 0.0f;

    uint4 kr0 = *(const uint4*)(kbase + (size_t)skey * NQKV);
    uint4 kr1 = *(const uint4*)(kbase + (size_t)skey * NQKV + 8);
    uint4 vr0 = *(const uint4*)(vbase + (size_t)skey * NQKV);
    uint4 vr1 = *(const uint4*)(vbase + (size_t)skey * NQKV + 8);

    for (int kt = 0; kt < ktiles; ++kt) {
      __syncthreads();
      *(uint4*)&smem[skey*72 + sp*16]           = kr0;
      *(uint4*)&smem[skey*72 + sp*16 + 8]       = kr1;
      *(uint4*)&smem[V0u + skey*72 + sp*16]     = vr0;
      *(uint4*)&smem[V0u + skey*72 + sp*16 + 8] = vr1;
      __syncthreads();

      if (kt + 1 < ktiles) {   // T14: issue next tile's loads before compute
        const u16* kp = kbase + (size_t)((kt+1)*64 + skey) * NQKV;
        const u16* vp = vbase + (size_t)((kt+1)*64 + skey) * NQKV;
        kr0 = *(const uint4*)kp; kr1 = *(const uint4*)(kp + 8);
        vr0 = *(const uint4*)vp; vr1 = *(const uint4*)(vp + 8);
      }

      if (kt*64 <= qw + 31) {
        // ---- S^T = K Q^T : two 32-key blocks ----
        f32x16 s0 = {}, s1 = {};
#pragma unroll
        for (int m = 0; m < 4; ++m) {
          bf16x8 k0 = *(const bf16x8*)&smem[(l31)*72      + m*16 + hh*8];
          bf16x8 k1 = *(const bf16x8*)&smem[(32 + l31)*72 + m*16 + hh*8];
          s0 = __builtin_amdgcn_mfma_f32_32x32x16_bf16(k0, qfrag[m], s0, 0,0,0);
          s1 = __builtin_amdgcn_mfma_f32_32x32x16_bf16(k1, qfrag[m], s1, 0,0,0);
        }

        // ---- causal mask (diagonal region only) ----
        if (kt*64 + 63 > qw) {
          const int kb0 = kt*64;
#pragma unroll
          for (int r = 0; r < 16; ++r) {
            const int crow = (r&3) + 8*(r>>2) + 4*hh;
            if (kb0 + crow > qi)      s0[r] = -1e30f;
            if (kb0 + 32 + crow > qi) s1[r] = -1e30f;
          }
        }

        // ---- per-lane softmax: in-lane max + one permlane swap ----
        float rm = s0[0];
#pragma unroll
        for (int r = 1; r < 16; ++r) rm = fmaxf(rm, s0[r]);
#pragma unroll
        for (int r = 0; r < 16; ++r) rm = fmaxf(rm, s1[r]);
        {
          uint2v t = plswap(__float_as_uint(rm), __float_as_uint(rm));
          rm = fmaxf(__uint_as_float(t[0]), __uint_as_float(t[1]));
        }
        if (__any(rm > m_run + 8.0f)) {     // defer-max THR=8 (log2 units)
          const float mn = fmaxf(m_run, rm);
          const float al = exp2f(m_run - mn);
          m_run = mn; l_part *= al;
#pragma unroll
          for (int r = 0; r < 16; ++r) { o0[r] *= al; o1[r] *= al; }
        }

        // ---- exp2 + in-register P pack (T12) ----
        pfu pf0, pf1, pf2, pf3;
        {
          float pe[16];
#pragma unroll
          for (int r = 0; r < 16; ++r) { pe[r] = exp2f(s0[r] - m_run); l_part += pe[r]; }
          unsigned a0 = cvtpk(pe[0],pe[1]),  a1 = cvtpk(pe[2],pe[3]);
          unsigned a2 = cvtpk(pe[4],pe[5]),  a3 = cvtpk(pe[6],pe[7]);
          uint2v x1 = plswap(a0, a2), x2 = plswap(a1, a3);
          pf0.u[0]=x1[0]; pf0.u[1]=x2[0]; pf0.u[2]=x1[1]; pf0.u[3]=x2[1];
          unsigned b0 = cvtpk(pe[8],pe[9]),  b1 = cvtpk(pe[10],pe[11]);
          unsigned b2 = cvtpk(pe[12],pe[13]), b3 = cvtpk(pe[14],pe[15]);
          uint2v x3 = plswap(b0, b2), x4 = plswap(b1, b3);
          pf1.u[0]=x3[0]; pf1.u[1]=x4[0]; pf1.u[2]=x3[1]; pf1.u[3]=x4[1];
        }
        {
          float pe[16];
#pragma unroll
          for (int r = 0; r < 16; ++r) { pe[r] = exp2f(s1[r] - m_run); l_part += pe[r]; }
          unsigned a0 = cvtpk(pe[0],pe[1]),  a1 = cvtpk(pe[2],pe[3]);
          unsigned a2 = cvtpk(pe[4],pe[5]),  a3 = cvtpk(pe[6],pe[7]);
          uint2v x1 = plswap(a0, a2), x2 = plswap(a1, a3);
          pf2.u[0]=x1[0]; pf2.u[1]=x2[0]; pf2.u[2]=x1[1]; pf2.u[3]=x2[1];
          unsigned b0 = cvtpk(pe[8],pe[9]),  b1 = cvtpk(pe[10],pe[11]);
          unsigned b2 = cvtpk(pe[12],pe[13]), b3 = cvtpk(pe[14],pe[15]);
          uint2v x3 = plswap(b0, b2), x4 = plswap(b1, b3);
          pf3.u[0]=x3[0]; pf3.u[1]=x4[0]; pf3.u[2]=x3[1]; pf3.u[3]=x4[1];
        }

        // ---- O^T += V^T P : 16 tr-reads, then 8 MFMAs ----
        short4v ta0,tb0,ta1,tb1,ta2,tb2,ta3,tb3,ta4,tb4,ta5,tb5,ta6,tb6,ta7,tb7;
        TRD(ta0, vaddr, "0");    TRD(tb0, vaddr, "576");   // c0 d2=0
        TRD(ta1, vaddr, "64");   TRD(tb1, vaddr, "640");   // c0 d2=1
        TRD(ta2, vaddr, "2304"); TRD(tb2, vaddr, "2880");  // c1 d2=0
        TRD(ta3, vaddr, "2368"); TRD(tb3, vaddr, "2944");  // c1 d2=1
        TRD(ta4, vaddr, "4608"); TRD(tb4, vaddr, "5184");  // c2 d2=0
        TRD(ta5, vaddr, "4672"); TRD(tb5, vaddr, "5248");  // c2 d2=1
        TRD(ta6, vaddr, "6912"); TRD(tb6, vaddr, "7488");  // c3 d2=0
        TRD(ta7, vaddr, "6976"); TRD(tb7, vaddr, "7552");  // c3 d2=1
        asm volatile("s_waitcnt lgkmcnt(0)" ::: "memory");
        __builtin_amdgcn_sched_barrier(0);
        trpair v00,v01,v10,v11,v20,v21,v30,v31;
        v00.h[0]=ta0; v00.h[1]=tb0;  v01.h[0]=ta1; v01.h[1]=tb1;
        v10.h[0]=ta2; v10.h[1]=tb2;  v11.h[0]=ta3; v11.h[1]=tb3;
        v20.h[0]=ta4; v20.h[1]=tb4;  v21.h[0]=ta5; v21.h[1]=tb5;
        v30.h[0]=ta6; v30.h[1]=tb6;  v31.h[0]=ta7; v31.h[1]=tb7;
        o0 = __builtin_amdgcn_mfma_f32_32x32x16_bf16(v00.v, pf0.v, o0, 0,0,0);
        o1 = __builtin_amdgcn_mfma_f32_32x32x16_bf16(v01.v, pf0.v, o1, 0,0,0);
        o0 = __builtin_amdgcn_mfma_f32_32x32x16_bf16(v10.v, pf1.v, o0, 0,0,0);
        o1 = __builtin_amdgcn_mfma_f32_32x32x16_bf16(v11.v, pf1.v, o1, 0,0,0);
        o0 = __builtin_amdgcn_mfma_f32_32x32x16_bf16(v20.v, pf2.v, o0, 0,0,0);
        o1 = __builtin_amdgcn_mfma_f32_32x32x16_bf16(v21.v, pf2.v, o1, 0,0,0);
        o0 = __builtin_amdgcn_mfma_f32_32x32x16_bf16(v30.v, pf3.v, o0, 0,0,0);
        o1 = __builtin_amdgcn_mfma_f32_32x32x16_bf16(v31.v, pf3.v, o1, 0,0,0);
      }
    }

    // ---- epilogue ----
    {
      uint2v t = plswap(__float_as_uint(l_part), __float_as_uint(l_part));
      l_part = __uint_as_float(t[0]) + __uint_as_float(t[1]);
    }
    const float inv = 1.0f / l_part;

    __syncthreads();   // all waves done with K/V before scratch reuse
#pragma unroll
    for (int k4 = 0; k4 < 4; ++k4) {
      bf16x4 pa, pb;
#pragma unroll
      for (int j = 0; j < 4; ++j) {
        pa[j] = (bf16_t)(o0[4*k4 + j] * inv);
        pb[j] = (bf16_t)(o1[4*k4 + j] * inv);
      }
      *(bf16x4*)&smem[w*2304 + l31*72 +      8*k4 + 4*hh] = pa;
      *(bf16x4*)&smem[w*2304 + l31*72 + 32 + 8*k4 + 4*hh] = pb;
    }
    u16* yp = y + ((size_t)(b*Tt + qi)) * Cc + head*64;
#pragma unroll
    for (int p = 0; p < 4; ++p) {
      bf16x8 row = *(const bf16x8*)&smem[w*2304 + l31*72 + p*16 + hh*8];
      *(bf16x8*)(yp + p*16 + hh*8) = row;
    }
    // next half's loop-top __syncthreads orders epilogue reads vs restaging
  }
}

// ---------------------------------------------------------------------------
extern "C" void kernel_launch(void* const* d_in, const int* in_sizes, int n_in,
                              void* d_out, int out_size, void* d_ws, size_t ws_size,
                              hipStream_t stream) {
  const float* x      = (const float*)d_in[0];
  const float* w_attn = (const float*)d_in[1];
  const float* b_attn = (const float*)d_in[2];
  const float* w_proj = (const float*)d_in[3];
  const float* b_proj = (const float*)d_in[4];
  float* out = (float*)d_out;

  char* ws = (char*)d_ws;
  u16*   xb    = (u16*)(ws + 0);          // 16 MB
  u16*   wab   = (u16*)(ws + 16777216);   // 6 MB
  u16*   wpb   = (u16*)(ws + 23068672);   // 2 MB
  u16*   qkvb  = (u16*)(ws + 25165824);   // 48 MB
  u16*   yb    = (u16*)(ws + 75497472);   // 16 MB
  float* sbias = (float*)(ws + 92274688); // 12 KB

  // convert inputs to bf16; fold 0.125*log2e into Wq rows and bq
  cvt_f32_bf16<<<4096, 256, 0, stream>>>(x,      xb,  0, 1.0f);
  cvt_f32_bf16<<<1536, 256, 0, stream>>>(w_attn, wab, (long)Cc*Cc, QSCALE);
  cvt_f32_bf16<<<512,  256, 0, stream>>>(w_proj, wpb, 0, 1.0f);
  scale_bias<<<12, 256, 0, stream>>>(b_attn, sbias);

  // 1) QKV projection (bf16 out, q pre-scaled)
  gemm_bf16<1><<<dim3(Mtot/128, NQKV/128), 256, 0, stream>>>(
      xb, wab, sbias, (void*)qkvb, Mtot, NQKV, Cc);

  // 2) causal attention (bf16 y)
  attn_kernel<<<dim3(8, Bb*Hh), 256, 0, stream>>>(qkvb, yb);

  // 3) output projection (f32 out)
  gemm_bf16<0><<<dim3(Mtot/128, Cc/128), 256, 0, stream>>>(
      yb, wpb, b_proj, (void*)out, Mtot, Cc, Cc);
}